// Round 3
// baseline (640.900 us; speedup 1.0000x reference)
//
#include <hip/hip_runtime.h>

typedef _Float16 v8h __attribute__((ext_vector_type(8)));
typedef float v16f __attribute__((ext_vector_type(16)));

// ---------------------------------------------------------------------------
// BT[o][ko*IN + i] = (ko<64) ? w2[ko, i*64+o] : b2[i*64+o], f16 [64, 65*IN]
// ---------------------------------------------------------------------------
__global__ void prep_bt_both(const float* __restrict__ w2_0, const float* __restrict__ b2_0,
                             _Float16* __restrict__ BT0,
                             const float* __restrict__ w2_1, const float* __restrict__ b2_1,
                             _Float16* __restrict__ BT1) {
    int idx = blockIdx.x * 256 + threadIdx.x;
    const int t0 = 64 * 2080, t1 = 64 * 4160;
    if (idx < t0) {
        int o = idx / 2080, kk = idx - o * 2080;
        int ko = kk / 32, i = kk - ko * 32;
        float v = (ko < 64) ? w2_0[ko * (32 * 64) + i * 64 + o] : b2_0[i * 64 + o];
        BT0[idx] = (_Float16)v;
    } else if (idx < t0 + t1) {
        int j = idx - t0;
        int o = j / 4160, kk = j - o * 4160;
        int ko = kk / 64, i = kk - ko * 64;
        float v = (ko < 64) ? w2_1[ko * (64 * 64) + i * 64 + o] : b2_1[i * 64 + o];
        BT1[j] = (_Float16)v;
    }
}

// relu1_ext [E, 66] f16 for BOTH layers: cols 0..63 = relu(ea@w1+b1), 64 = 1, 65 = 0
__global__ void prep_r1_both(const float* __restrict__ ea,
                             const float* __restrict__ w1_0, const float* __restrict__ b1_0,
                             const float* __restrict__ w1_1, const float* __restrict__ b1_1,
                             _Float16* __restrict__ r1_0, _Float16* __restrict__ r1_1, int E) {
    int idx = blockIdx.x * 256 + threadIdx.x;
    if (idx >= E * 66) return;
    int e = idx / 66, j = idx - e * 66;
    float v0, v1;
    if (j < 64) {
        float a = ea[e * 2], b = ea[e * 2 + 1];
        v0 = fmaxf(a * w1_0[j] + b * w1_0[64 + j] + b1_0[j], 0.f);
        v1 = fmaxf(a * w1_1[j] + b * w1_1[64 + j] + b1_1[j], 0.f);
    } else if (j == 64) { v0 = 1.f; v1 = 1.f; }
    else               { v0 = 0.f; v1 = 0.f; }
    r1_0[idx] = (_Float16)v0;
    r1_1[idx] = (_Float16)v1;
}

// agg0[n,o] = bias0[o] + sum_i x[n,i]*root0[i,o]; also emits x in f16
__global__ void node_root_cvt(const float* __restrict__ x, const float* __restrict__ root,
                              const float* __restrict__ bias, float* __restrict__ agg,
                              _Float16* __restrict__ xb, int N) {
    int idx = blockIdx.x * 256 + threadIdx.x;
    if (idx >= N * 64) return;
    int n = idx >> 6, o = idx & 63;
    float s = bias[o];
    const float* xr = x + (size_t)n * 32;
    #pragma unroll 8
    for (int i = 0; i < 32; ++i) s += xr[i] * root[i * 64 + o];
    agg[idx] = s;
    if (o < 32) xb[n * 32 + o] = (_Float16)xr[o];
}

// x1b = f16(relu(agg0)); agg1[n,o] = bias1[o] + sum_i relu(agg0[n,i])*root1[i,o]
__global__ void mid_kernel(const float* __restrict__ agg0, const float* __restrict__ root1,
                           const float* __restrict__ bias1, _Float16* __restrict__ x1b,
                           float* __restrict__ agg1, int N) {
    int idx = blockIdx.x * 256 + threadIdx.x;
    if (idx >= N * 64) return;
    int n = idx >> 6, o = idx & 63;
    const float* ar = agg0 + (size_t)n * 64;
    float s = bias1[o];
    #pragma unroll 8
    for (int i = 0; i < 64; ++i) s += fmaxf(ar[i], 0.f) * root1[i * 64 + o];
    agg1[idx] = s;
    x1b[idx] = (_Float16)fmaxf(agg0[idx], 0.f);
}

__global__ void final_relu(const float* __restrict__ agg1, float* __restrict__ out, int n) {
    int idx = blockIdx.x * 256 + threadIdx.x;
    if (idx < n) out[idx] = fmaxf(agg1[idx], 0.f);
}

// ---------------------------------------------------------------------------
// Edge GEMM v3: 64-edge tile, 4 waves, K-quarter per wave, register
// double-buffered B prefetch (depth 1) to hide L2 latency. Cross-wave reduce
// via LDS atomicAdd into one zero-initialized buffer, then one global atomic
// per output element.
// ---------------------------------------------------------------------------
template<int IN_C>
__global__ __launch_bounds__(256, 3)
void edge_gemm(const _Float16* __restrict__ r1, const _Float16* __restrict__ xb,
               const _Float16* __restrict__ BT, const int* __restrict__ srcI,
               const int* __restrict__ dstI, float* __restrict__ agg, int E) {
    constexpr int KT  = 65 * IN_C;   // total K
    constexpr int PH  = IN_C / 16;   // 16-wide K-steps per k_outer
    constexpr int CPR = IN_C / 8;    // 16B chunks per x row

    __shared__ _Float16 sh_r1[64][66];
    __shared__ _Float16 sh_x[64][IN_C];
    __shared__ int sh_dst[64];
    __shared__ float buf[64][65];

    int tid = threadIdx.x;
    int ebase = blockIdx.x * 64;
    int valid = E - ebase; if (valid > 64) valid = 64;

    if (tid < 64) sh_dst[tid] = (tid < valid) ? dstI[ebase + tid] : 0;

    {   // relu1 tile: rows contiguous (33 dwords each), flat copy
        const unsigned int* g = (const unsigned int*)(r1 + (size_t)ebase * 66);
        unsigned int* s = (unsigned int*)&sh_r1[0][0];
        for (int i = tid; i < valid * 33; i += 256) s[i] = g[i];
    }
    // gathered x tile
    for (int i = tid; i < 64 * CPR; i += 256) {
        int r = i / CPR, c = i - r * CPR;
        int sidx = (r < valid) ? srcI[ebase + r] : 0;
        *(uint4*)&sh_x[r][c * 8] = *(const uint4*)(xb + (size_t)sidx * IN_C + (size_t)c * 8);
    }
    // zero the reduce buffer
    {
        float* bf = &buf[0][0];
        for (int i = tid; i < 64 * 65; i += 256) bf[i] = 0.f;
    }
    __syncthreads();

    int wv = tid >> 6, lane = tid & 63, ln = lane & 31, g2 = lane >> 5;
    int mr0 = ln, mr1 = ln + 32;

    // x slices in registers
    v8h xs0[PH], xs1[PH];
    #pragma unroll
    for (int p = 0; p < PH; ++p) {
        xs0[p] = *(const v8h*)&sh_x[mr0][p * 16 + g2 * 8];
        xs1[p] = *(const v8h*)&sh_x[mr1][p * 16 + g2 * 8];
    }

    v16f acc00 = {0,0,0,0,0,0,0,0,0,0,0,0,0,0,0,0};
    v16f acc01 = acc00, acc10 = acc00, acc11 = acc00;

    const _Float16* bp0 = BT + (size_t)ln * KT + g2 * 8;
    const _Float16* bp1 = bp0 + (size_t)32 * KT;

    int kb = (wv * 65) >> 2, ke = ((wv + 1) * 65) >> 2;  // per-wave K quarter

    // software pipeline: double-buffered B fragments + r1 scalars
    v8h bb0[2][PH], bb1[2][PH];
    _Float16 sv0b[2], sv1b[2];

    auto loadB = [&](int slot, int ko) {
        #pragma unroll
        for (int p = 0; p < PH; ++p) {
            int kk = ko * IN_C + p * 16;
            bb0[slot][p] = *(const v8h*)(bp0 + kk);
            bb1[slot][p] = *(const v8h*)(bp1 + kk);
        }
        sv0b[slot] = sh_r1[mr0][ko];
        sv1b[slot] = sh_r1[mr1][ko];
    };
    auto comp = [&](int slot) {
        #pragma unroll
        for (int p = 0; p < PH; ++p) {
            v8h a0 = xs0[p] * sv0b[slot];
            v8h a1 = xs1[p] * sv1b[slot];
            acc00 = __builtin_amdgcn_mfma_f32_32x32x16_f16(a0, bb0[slot][p], acc00, 0, 0, 0);
            acc01 = __builtin_amdgcn_mfma_f32_32x32x16_f16(a0, bb1[slot][p], acc01, 0, 0, 0);
            acc10 = __builtin_amdgcn_mfma_f32_32x32x16_f16(a1, bb0[slot][p], acc10, 0, 0, 0);
            acc11 = __builtin_amdgcn_mfma_f32_32x32x16_f16(a1, bb1[slot][p], acc11, 0, 0, 0);
        }
    };

    int ko = kb;
    loadB(0, ko);
    while (true) {
        if (ko + 1 < ke) loadB(1, ko + 1);
        comp(0);
        ++ko; if (ko >= ke) break;
        if (ko + 1 < ke) loadB(0, ko + 1);
        comp(1);
        ++ko; if (ko >= ke) break;
    }

    // cross-wave reduce via LDS atomics (2-way bank aliasing only; stride 65)
    auto emit = [&](const v16f& c, int mf, int nf) {
        int col = nf * 32 + ln;
        #pragma unroll
        for (int r = 0; r < 16; ++r) {
            int row = mf * 32 + 4 * g2 + (r & 3) + 8 * (r >> 2);
            atomicAdd(&buf[row][col], c[r]);
        }
    };
    emit(acc00, 0, 0); emit(acc01, 0, 1);
    emit(acc10, 1, 0); emit(acc11, 1, 1);
    __syncthreads();

    // single global atomic per output element
    for (int t = tid; t < 64 * 64; t += 256) {
        int row = t >> 6, col = t & 63;
        if (row < valid)
            atomicAdd(&agg[(size_t)sh_dst[row] * 64 + col], buf[row][col]);
    }
}

// ---------------------------------------------------------------------------
extern "C" void kernel_launch(void* const* d_in, const int* in_sizes, int n_in,
                              void* d_out, int out_size, void* d_ws, size_t ws_size,
                              hipStream_t stream) {
    const float* x      = (const float*)d_in[0];
    const int*   ei     = (const int*)d_in[1];
    const float* ea     = (const float*)d_in[2];
    const float* w1_0   = (const float*)d_in[3];
    const float* b1_0   = (const float*)d_in[4];
    const float* w2_0   = (const float*)d_in[5];
    const float* b2_0   = (const float*)d_in[6];
    const float* root_0 = (const float*)d_in[7];
    const float* bias_0 = (const float*)d_in[8];
    const float* w1_1   = (const float*)d_in[9];
    const float* b1_1   = (const float*)d_in[10];
    const float* w2_1   = (const float*)d_in[11];
    const float* b2_1   = (const float*)d_in[12];
    const float* root_1 = (const float*)d_in[13];
    const float* bias_1 = (const float*)d_in[14];
    float* out = (float*)d_out;

    int N = in_sizes[0] / 32;
    int E = in_sizes[1] / 2;
    const int* srcI = ei;
    const int* dstI = ei + E;

    char* ws = (char*)d_ws;
    size_t off = 0;
    auto carve = [&](size_t bytes) {
        void* p = ws + off;
        off += (bytes + 255) & ~(size_t)255;
        return p;
    };
    _Float16* BT0  = (_Float16*)carve((size_t)64 * 2080 * 2);
    _Float16* BT1  = (_Float16*)carve((size_t)64 * 4160 * 2);
    _Float16* R10  = (_Float16*)carve((size_t)E * 66 * 2);
    _Float16* R11  = (_Float16*)carve((size_t)E * 66 * 2);
    _Float16* XB0  = (_Float16*)carve((size_t)N * 32 * 2);
    _Float16* X1B  = (_Float16*)carve((size_t)N * 64 * 2);
    float*    AGG0 = (float*)carve((size_t)N * 64 * 4);
    float*    AGG1 = (float*)carve((size_t)N * 64 * 4);

    int tbt = 64 * 2080 + 64 * 4160;
    prep_bt_both<<<(tbt + 255) / 256, 256, 0, stream>>>(w2_0, b2_0, BT0, w2_1, b2_1, BT1);
    prep_r1_both<<<(E * 66 + 255) / 256, 256, 0, stream>>>(ea, w1_0, b1_0, w1_1, b1_1, R10, R11, E);
    node_root_cvt<<<(N * 64 + 255) / 256, 256, 0, stream>>>(x, root_0, bias_0, AGG0, XB0, N);

    int gblocks = (E + 63) / 64;
    edge_gemm<32><<<gblocks, 256, 0, stream>>>(R10, XB0, BT0, srcI, dstI, AGG0, E);

    mid_kernel<<<(N * 64 + 255) / 256, 256, 0, stream>>>(AGG0, root_1, bias_1, X1B, AGG1, N);

    edge_gemm<64><<<gblocks, 256, 0, stream>>>(R11, X1B, BT1, srcI, dstI, AGG1, E);

    final_relu<<<(N * 64 + 255) / 256, 256, 0, stream>>>(AGG1, out, N * 64);
}

// Round 4
// 345.269 us; speedup vs baseline: 1.8562x; 1.8562x over previous
//
#include <hip/hip_runtime.h>

typedef _Float16 v8h __attribute__((ext_vector_type(8)));
typedef float v16f __attribute__((ext_vector_type(16)));

// ---------------------------------------------------------------------------
// BF: B in MFMA-fragment order. Fragment f = kk16*2 + nf holds, at
// [lane*8 + j], the value B[k = kk16*16 + (lane>>5)*8 + j][o = nf*32 + (lane&31)]
// where B[k][o] = (ko<64) ? w2[ko, i*64+o] : b2[i*64+o], ko=k/IN, i=k%IN.
// A wave's fragment load is 64 lanes x 16B contiguous = 1KB coalesced.
// ---------------------------------------------------------------------------
__global__ void prep_bf_both(const float* __restrict__ w2_0, const float* __restrict__ b2_0,
                             _Float16* __restrict__ BF0,
                             const float* __restrict__ w2_1, const float* __restrict__ b2_1,
                             _Float16* __restrict__ BF1) {
    int idx = blockIdx.x * 256 + threadIdx.x;
    const int n0 = 130 * 2 * 512;   // layer0: KT0/16=130 kk16-steps
    const int n1 = 260 * 2 * 512;   // layer1: KT1/16=260
    const float* w2; const float* b2; _Float16* BF; int IN, rel;
    if (idx < n0)           { w2 = w2_0; b2 = b2_0; BF = BF0; IN = 32; rel = idx; }
    else if (idx < n0 + n1) { w2 = w2_1; b2 = b2_1; BF = BF1; IN = 64; rel = idx - n0; }
    else return;
    int j = rel & 7, lane = (rel >> 3) & 63, f = rel >> 9;
    int nf = f & 1, kk16 = f >> 1;
    int ln = lane & 31, g2 = lane >> 5;
    int k = kk16 * 16 + g2 * 8 + j;
    int ko = k / IN, i = k - ko * IN;
    int o = nf * 32 + ln;
    float v = (ko < 64) ? w2[ko * (IN * 64) + i * 64 + o] : b2[i * 64 + o];
    BF[rel] = (_Float16)v;
}

// relu1_ext [E, 66] f16 for BOTH layers: cols 0..63 = relu(ea@w1+b1), 64 = 1, 65 = 0
__global__ void prep_r1_both(const float* __restrict__ ea,
                             const float* __restrict__ w1_0, const float* __restrict__ b1_0,
                             const float* __restrict__ w1_1, const float* __restrict__ b1_1,
                             _Float16* __restrict__ r1_0, _Float16* __restrict__ r1_1, int E) {
    int idx = blockIdx.x * 256 + threadIdx.x;
    if (idx >= E * 66) return;
    int e = idx / 66, j = idx - e * 66;
    float v0, v1;
    if (j < 64) {
        float a = ea[e * 2], b = ea[e * 2 + 1];
        v0 = fmaxf(a * w1_0[j] + b * w1_0[64 + j] + b1_0[j], 0.f);
        v1 = fmaxf(a * w1_1[j] + b * w1_1[64 + j] + b1_1[j], 0.f);
    } else if (j == 64) { v0 = 1.f; v1 = 1.f; }
    else               { v0 = 0.f; v1 = 0.f; }
    r1_0[idx] = (_Float16)v0;
    r1_1[idx] = (_Float16)v1;
}

// agg0[n,o] = bias0[o] + sum_i x[n,i]*root0[i,o]; also emits x in f16
__global__ void node_root_cvt(const float* __restrict__ x, const float* __restrict__ root,
                              const float* __restrict__ bias, float* __restrict__ agg,
                              _Float16* __restrict__ xb, int N) {
    int idx = blockIdx.x * 256 + threadIdx.x;
    if (idx >= N * 64) return;
    int n = idx >> 6, o = idx & 63;
    float s = bias[o];
    const float* xr = x + (size_t)n * 32;
    #pragma unroll 8
    for (int i = 0; i < 32; ++i) s += xr[i] * root[i * 64 + o];
    agg[idx] = s;
    if (o < 32) xb[n * 32 + o] = (_Float16)xr[o];
}

// x1b = f16(relu(agg0)); agg1[n,o] = bias1[o] + sum_i relu(agg0[n,i])*root1[i,o]
__global__ void mid_kernel(const float* __restrict__ agg0, const float* __restrict__ root1,
                           const float* __restrict__ bias1, _Float16* __restrict__ x1b,
                           float* __restrict__ agg1, int N) {
    int idx = blockIdx.x * 256 + threadIdx.x;
    if (idx >= N * 64) return;
    int n = idx >> 6, o = idx & 63;
    const float* ar = agg0 + (size_t)n * 64;
    float s = bias1[o];
    #pragma unroll 8
    for (int i = 0; i < 64; ++i) s += fmaxf(ar[i], 0.f) * root1[i * 64 + o];
    agg1[idx] = s;
    x1b[idx] = (_Float16)fmaxf(agg0[idx], 0.f);
}

__global__ void final_relu(const float* __restrict__ agg1, float* __restrict__ out, int n) {
    int idx = blockIdx.x * 256 + threadIdx.x;
    if (idx < n) out[idx] = fmaxf(agg1[idx], 0.f);
}

// ---------------------------------------------------------------------------
// Edge GEMM v4: 64-edge tile, 4 waves, K-quarter per wave (R2 structure — no
// rolling pipeline, spill-proven). B read from pre-swizzled BF in fragment
// order: each fragment load is 1KB fully coalesced (8 cachelines vs 32 for
// the old row-strided BT). Cross-wave reduce via LDS atomicAdd into one
// zeroed buffer, then one global atomic per output element.
// ---------------------------------------------------------------------------
template<int IN_C>
__global__ __launch_bounds__(256, 3)
void edge_gemm(const _Float16* __restrict__ r1, const _Float16* __restrict__ xb,
               const _Float16* __restrict__ BF, const int* __restrict__ srcI,
               const int* __restrict__ dstI, float* __restrict__ agg, int E) {
    constexpr int PH  = IN_C / 16;   // 16-wide K-steps per k_outer
    constexpr int CPR = IN_C / 8;    // 16B chunks per x row

    __shared__ _Float16 sh_r1[64][66];
    __shared__ _Float16 sh_x[64][IN_C];
    __shared__ int sh_dst[64];
    __shared__ float buf[64][65];

    int tid = threadIdx.x;
    int ebase = blockIdx.x * 64;
    int valid = E - ebase; if (valid > 64) valid = 64;

    if (tid < 64) sh_dst[tid] = (tid < valid) ? dstI[ebase + tid] : 0;

    {   // relu1 tile: rows contiguous (33 dwords each), flat copy
        const unsigned int* g = (const unsigned int*)(r1 + (size_t)ebase * 66);
        unsigned int* s = (unsigned int*)&sh_r1[0][0];
        for (int i = tid; i < valid * 33; i += 256) s[i] = g[i];
    }
    // gathered x tile
    for (int i = tid; i < 64 * CPR; i += 256) {
        int r = i / CPR, c = i - r * CPR;
        int sidx = (r < valid) ? srcI[ebase + r] : 0;
        *(uint4*)&sh_x[r][c * 8] = *(const uint4*)(xb + (size_t)sidx * IN_C + (size_t)c * 8);
    }
    // zero the reduce buffer
    {
        float* bf = &buf[0][0];
        for (int i = tid; i < 64 * 65; i += 256) bf[i] = 0.f;
    }
    __syncthreads();

    int wv = tid >> 6, lane = tid & 63, ln = lane & 31, g2 = lane >> 5;
    int mr0 = ln, mr1 = ln + 32;

    // x slices in registers
    v8h xs0[PH], xs1[PH];
    #pragma unroll
    for (int p = 0; p < PH; ++p) {
        xs0[p] = *(const v8h*)&sh_x[mr0][p * 16 + g2 * 8];
        xs1[p] = *(const v8h*)&sh_x[mr1][p * 16 + g2 * 8];
    }

    v16f acc00 = {0,0,0,0,0,0,0,0,0,0,0,0,0,0,0,0};
    v16f acc01 = acc00, acc10 = acc00, acc11 = acc00;

    const _Float16* bfp = BF + (size_t)lane * 8;   // lane offset within fragment

    int kb = (wv * 65) >> 2, ke = ((wv + 1) * 65) >> 2;  // per-wave K quarter
    for (int ko = kb; ko < ke; ++ko) {
        _Float16 sv0 = sh_r1[mr0][ko];
        _Float16 sv1 = sh_r1[mr1][ko];
        v8h b0[PH], b1[PH];
        #pragma unroll
        for (int p = 0; p < PH; ++p) {   // batch coalesced fragment loads
            int f = (ko * PH + p) * 2;
            b0[p] = *(const v8h*)(bfp + (size_t)f * 512);
            b1[p] = *(const v8h*)(bfp + (size_t)(f + 1) * 512);
        }
        #pragma unroll
        for (int p = 0; p < PH; ++p) {
            v8h a0 = xs0[p] * sv0;
            v8h a1 = xs1[p] * sv1;
            acc00 = __builtin_amdgcn_mfma_f32_32x32x16_f16(a0, b0[p], acc00, 0, 0, 0);
            acc01 = __builtin_amdgcn_mfma_f32_32x32x16_f16(a0, b1[p], acc01, 0, 0, 0);
            acc10 = __builtin_amdgcn_mfma_f32_32x32x16_f16(a1, b0[p], acc10, 0, 0, 0);
            acc11 = __builtin_amdgcn_mfma_f32_32x32x16_f16(a1, b1[p], acc11, 0, 0, 0);
        }
    }

    // cross-wave reduce via LDS atomics (stride 65 → 2-way aliasing only, free)
    auto emit = [&](const v16f& c, int mf, int nf) {
        int col = nf * 32 + ln;
        #pragma unroll
        for (int r = 0; r < 16; ++r) {
            int row = mf * 32 + 4 * g2 + (r & 3) + 8 * (r >> 2);
            atomicAdd(&buf[row][col], c[r]);
        }
    };
    emit(acc00, 0, 0); emit(acc01, 0, 1);
    emit(acc10, 1, 0); emit(acc11, 1, 1);
    __syncthreads();

    // single global atomic per output element
    for (int t = tid; t < 64 * 64; t += 256) {
        int row = t >> 6, col = t & 63;
        if (row < valid)
            atomicAdd(&agg[(size_t)sh_dst[row] * 64 + col], buf[row][col]);
    }
}

// ---------------------------------------------------------------------------
extern "C" void kernel_launch(void* const* d_in, const int* in_sizes, int n_in,
                              void* d_out, int out_size, void* d_ws, size_t ws_size,
                              hipStream_t stream) {
    const float* x      = (const float*)d_in[0];
    const int*   ei     = (const int*)d_in[1];
    const float* ea     = (const float*)d_in[2];
    const float* w1_0   = (const float*)d_in[3];
    const float* b1_0   = (const float*)d_in[4];
    const float* w2_0   = (const float*)d_in[5];
    const float* b2_0   = (const float*)d_in[6];
    const float* root_0 = (const float*)d_in[7];
    const float* bias_0 = (const float*)d_in[8];
    const float* w1_1   = (const float*)d_in[9];
    const float* b1_1   = (const float*)d_in[10];
    const float* w2_1   = (const float*)d_in[11];
    const float* b2_1   = (const float*)d_in[12];
    const float* root_1 = (const float*)d_in[13];
    const float* bias_1 = (const float*)d_in[14];
    float* out = (float*)d_out;

    int N = in_sizes[0] / 32;
    int E = in_sizes[1] / 2;
    const int* srcI = ei;
    const int* dstI = ei + E;

    char* ws = (char*)d_ws;
    size_t off = 0;
    auto carve = [&](size_t bytes) {
        void* p = ws + off;
        off += (bytes + 255) & ~(size_t)255;
        return p;
    };
    _Float16* BF0  = (_Float16*)carve((size_t)130 * 2 * 512 * 2);
    _Float16* BF1  = (_Float16*)carve((size_t)260 * 2 * 512 * 2);
    _Float16* R10  = (_Float16*)carve((size_t)E * 66 * 2);
    _Float16* R11  = (_Float16*)carve((size_t)E * 66 * 2);
    _Float16* XB0  = (_Float16*)carve((size_t)N * 32 * 2);
    _Float16* X1B  = (_Float16*)carve((size_t)N * 64 * 2);
    float*    AGG0 = (float*)carve((size_t)N * 64 * 4);
    float*    AGG1 = (float*)carve((size_t)N * 64 * 4);

    int tbf = (130 + 260) * 2 * 512;
    prep_bf_both<<<(tbf + 255) / 256, 256, 0, stream>>>(w2_0, b2_0, BF0, w2_1, b2_1, BF1);
    prep_r1_both<<<(E * 66 + 255) / 256, 256, 0, stream>>>(ea, w1_0, b1_0, w1_1, b1_1, R10, R11, E);
    node_root_cvt<<<(N * 64 + 255) / 256, 256, 0, stream>>>(x, root_0, bias_0, AGG0, XB0, N);

    int gblocks = (E + 63) / 64;
    edge_gemm<32><<<gblocks, 256, 0, stream>>>(R10, XB0, BF0, srcI, dstI, AGG0, E);

    mid_kernel<<<(N * 64 + 255) / 256, 256, 0, stream>>>(AGG0, root_1, bias_1, X1B, AGG1, N);

    edge_gemm<64><<<gblocks, 256, 0, stream>>>(R11, X1B, BF1, srcI, dstI, AGG1, E);

    final_relu<<<(N * 64 + 255) / 256, 256, 0, stream>>>(AGG1, out, N * 64);
}

// Round 5
// 198.843 us; speedup vs baseline: 3.2231x; 1.7364x over previous
//
#include <hip/hip_runtime.h>

typedef _Float16 v8h __attribute__((ext_vector_type(8)));
typedef float v16f __attribute__((ext_vector_type(16)));

// ---------------------------------------------------------------------------
// BF: B in MFMA-fragment order, padded to 66 ko (pad rows = 0).
// Fragment f = kk16*2 + nf holds at [lane*8 + j]:
//   B[k = kk16*16 + (lane>>5)*8 + j][o = nf*32 + (lane&31)]
// where B[k][o] = (ko<64) ? w2[ko, i*64+o] : (ko==64 ? b2[i*64+o] : 0),
// ko = k/IN, i = k%IN. Layer0: 264 frags, layer1: 528 frags (512 halfs each).
// ---------------------------------------------------------------------------
__global__ void prep_bf_both(const float* __restrict__ w2_0, const float* __restrict__ b2_0,
                             _Float16* __restrict__ BF0,
                             const float* __restrict__ w2_1, const float* __restrict__ b2_1,
                             _Float16* __restrict__ BF1) {
    int idx = blockIdx.x * 256 + threadIdx.x;
    const int n0 = 264 * 512;   // layer0: 66 ko * 2 kk16/ko * 2 nf
    const int n1 = 528 * 512;   // layer1: 66 ko * 4 kk16/ko * 2 nf
    const float* w2; const float* b2; _Float16* BF; int IN, rel;
    if (idx < n0)           { w2 = w2_0; b2 = b2_0; BF = BF0; IN = 32; rel = idx; }
    else if (idx < n0 + n1) { w2 = w2_1; b2 = b2_1; BF = BF1; IN = 64; rel = idx - n0; }
    else return;
    int j = rel & 7, lane = (rel >> 3) & 63, f = rel >> 9;
    int nf = f & 1, kk16 = f >> 1;
    int ln = lane & 31, g2 = lane >> 5;
    int k = kk16 * 16 + g2 * 8 + j;
    int ko = k / IN, i = k - ko * IN;
    int o = nf * 32 + ln;
    float v = (ko < 64) ? w2[ko * (IN * 64) + i * 64 + o]
            : (ko == 64 ? b2[i * 64 + o] : 0.f);
    BF[rel] = (_Float16)v;
}

// agg0[n,o] = bias0[o] + sum_i x[n,i]*root0[i,o]; also emits x in f16
__global__ void node_root_cvt(const float* __restrict__ x, const float* __restrict__ root,
                              const float* __restrict__ bias, float* __restrict__ agg,
                              _Float16* __restrict__ xb, int N) {
    int idx = blockIdx.x * 256 + threadIdx.x;
    if (idx >= N * 64) return;
    int n = idx >> 6, o = idx & 63;
    float s = bias[o];
    const float* xr = x + (size_t)n * 32;
    #pragma unroll 8
    for (int i = 0; i < 32; ++i) s += xr[i] * root[i * 64 + o];
    agg[idx] = s;
    if (o < 32) xb[n * 32 + o] = (_Float16)xr[o];
}

// x1b = f16(relu(agg0)); agg1[n,o] = bias1[o] + sum_i relu(agg0[n,i])*root1[i,o]
__global__ void mid_kernel(const float* __restrict__ agg0, const float* __restrict__ root1,
                           const float* __restrict__ bias1, _Float16* __restrict__ x1b,
                           float* __restrict__ agg1, int N) {
    int idx = blockIdx.x * 256 + threadIdx.x;
    if (idx >= N * 64) return;
    int n = idx >> 6, o = idx & 63;
    const float* ar = agg0 + (size_t)n * 64;
    float s = bias1[o];
    #pragma unroll 8
    for (int i = 0; i < 64; ++i) s += fmaxf(ar[i], 0.f) * root1[i * 64 + o];
    agg1[idx] = s;
    x1b[idx] = (_Float16)fmaxf(agg0[idx], 0.f);
}

__global__ void final_relu(const float* __restrict__ agg1, float* __restrict__ out, int n) {
    int idx = blockIdx.x * 256 + threadIdx.x;
    if (idx < n) out[idx] = fmaxf(agg1[idx], 0.f);
}

// ---------------------------------------------------------------------------
// Edge GEMM v5: 64-edge tile, 4 waves; wave w owns quadrant (mf=w&1, nf=w>>1)
// with ONE 32x32 accumulator; all waves run the FULL K. B staged through LDS
// (double-buffered, chunk = 2 ko) with a register relay: prefetch chunk c+1
// into regs, compute chunk c from LDS, ds_write c+1, one barrier. r1 (edge
// MLP layer 1) computed in-kernel, never touching global memory. Epilogue:
// direct global atomics per quadrant (no cross-wave reduce).
// ---------------------------------------------------------------------------
template<int IN_C>
__global__ __launch_bounds__(256, 3)
void edge_gemm(const float* __restrict__ ea,
               const float* __restrict__ w1, const float* __restrict__ b1,
               const _Float16* __restrict__ xb, const _Float16* __restrict__ BF,
               const int* __restrict__ srcI, const int* __restrict__ dstI,
               float* __restrict__ agg, int E) {
    constexpr int PH  = IN_C / 16;        // kk16-steps per ko
    constexpr int FR  = 4 * PH;           // fragments per chunk (2 ko * PH * 2 nf)
    constexpr int CH  = FR * 512;         // halfs per chunk
    constexpr int LD4 = FR / 4;           // uint4 per thread per chunk
    constexpr int NC  = 33;               // chunks (66 ko total, ko 65 is zero pad)
    constexpr int CPR = IN_C / 8;         // 16B chunks per x row

    __shared__ __align__(16) _Float16 sh_b[2][CH];
    __shared__ __align__(16) _Float16 sh_x[64][IN_C];
    __shared__ _Float16 sh_r1[64][66];
    __shared__ int sh_dst[64];

    int tid = threadIdx.x;
    int ebase = blockIdx.x * 64;
    int valid = E - ebase; if (valid > 64) valid = 64;

    if (tid < 64) {
        sh_dst[tid] = (tid < valid) ? dstI[ebase + tid] : 0;
        sh_r1[tid][64] = (_Float16)1.f;
        sh_r1[tid][65] = (_Float16)0.f;
    }
    // r1 tile computed in-kernel: relu(ea @ w1 + b1), 64 edges x 64 cols
    for (int i = tid; i < 64 * 64; i += 256) {
        int e = i >> 6, j = i & 63;
        int ge = (e < valid) ? (ebase + e) : ebase;
        float a0 = ea[ge * 2], a1 = ea[ge * 2 + 1];
        sh_r1[e][j] = (_Float16)fmaxf(a0 * w1[j] + a1 * w1[64 + j] + b1[j], 0.f);
    }
    // gathered x tile
    for (int i = tid; i < 64 * CPR; i += 256) {
        int r = i / CPR, c = i - r * CPR;
        int sidx = (r < valid) ? srcI[ebase + r] : 0;
        *(uint4*)&sh_x[r][c * 8] = *(const uint4*)(xb + (size_t)sidx * IN_C + (size_t)c * 8);
    }
    // preload chunk 0 straight into LDS
    const uint4* BF4 = (const uint4*)BF;
    uint4 st[LD4];
    #pragma unroll
    for (int q = 0; q < LD4; ++q) st[q] = BF4[(size_t)q * 256 + tid];
    #pragma unroll
    for (int q = 0; q < LD4; ++q) ((uint4*)sh_b[0])[q * 256 + tid] = st[q];
    __syncthreads();

    int wv = tid >> 6, lane = tid & 63, ln = lane & 31, g2 = lane >> 5;
    int mf = wv & 1, nf = wv >> 1;
    int mrow = mf * 32 + ln;

    v8h xs[PH];
    #pragma unroll
    for (int p = 0; p < PH; ++p) xs[p] = *(const v8h*)&sh_x[mrow][p * 16 + g2 * 8];

    v16f acc = {0,0,0,0,0,0,0,0,0,0,0,0,0,0,0,0};

    for (int c = 0; c < NC; ++c) {
        // prefetch next chunk into registers (latency hidden by compute below)
        if (c + 1 < NC) {
            size_t base = (size_t)(c + 1) * (CH / 8);
            #pragma unroll
            for (int q = 0; q < LD4; ++q) st[q] = BF4[base + q * 256 + tid];
        }
        // compute chunk c from LDS
        const _Float16* bb = sh_b[c & 1];
        #pragma unroll
        for (int dk = 0; dk < 2; ++dk) {
            _Float16 sv = sh_r1[mrow][c * 2 + dk];
            #pragma unroll
            for (int p = 0; p < PH; ++p) {
                int fi = (dk * PH + p) * 2 + nf;
                v8h b = *(const v8h*)(bb + fi * 512 + lane * 8);
                v8h a = xs[p] * sv;
                acc = __builtin_amdgcn_mfma_f32_32x32x16_f16(a, b, acc, 0, 0, 0);
            }
        }
        // relay prefetch into the other LDS buffer; one barrier per chunk
        if (c + 1 < NC) {
            #pragma unroll
            for (int q = 0; q < LD4; ++q) ((uint4*)sh_b[(c + 1) & 1])[q * 256 + tid] = st[q];
        }
        __syncthreads();
    }

    // epilogue: direct global atomics for this wave's 32x32 quadrant.
    // C/D layout: col = lane&31, row = 4*(lane>>5) + (r&3) + 8*(r>>2)
    int colbase = nf * 32 + ln;
    #pragma unroll
    for (int r = 0; r < 16; ++r) {
        int row = mf * 32 + 4 * g2 + (r & 3) + 8 * (r >> 2);
        if (row < valid)
            atomicAdd(&agg[(size_t)sh_dst[row] * 64 + colbase], acc[r]);
    }
}

// ---------------------------------------------------------------------------
extern "C" void kernel_launch(void* const* d_in, const int* in_sizes, int n_in,
                              void* d_out, int out_size, void* d_ws, size_t ws_size,
                              hipStream_t stream) {
    const float* x      = (const float*)d_in[0];
    const int*   ei     = (const int*)d_in[1];
    const float* ea     = (const float*)d_in[2];
    const float* w1_0   = (const float*)d_in[3];
    const float* b1_0   = (const float*)d_in[4];
    const float* w2_0   = (const float*)d_in[5];
    const float* b2_0   = (const float*)d_in[6];
    const float* root_0 = (const float*)d_in[7];
    const float* bias_0 = (const float*)d_in[8];
    const float* w1_1   = (const float*)d_in[9];
    const float* b1_1   = (const float*)d_in[10];
    const float* w2_1   = (const float*)d_in[11];
    const float* b2_1   = (const float*)d_in[12];
    const float* root_1 = (const float*)d_in[13];
    const float* bias_1 = (const float*)d_in[14];
    float* out = (float*)d_out;

    int N = in_sizes[0] / 32;
    int E = in_sizes[1] / 2;
    const int* srcI = ei;
    const int* dstI = ei + E;

    char* ws = (char*)d_ws;
    size_t off = 0;
    auto carve = [&](size_t bytes) {
        void* p = ws + off;
        off += (bytes + 255) & ~(size_t)255;
        return p;
    };
    _Float16* BF0  = (_Float16*)carve((size_t)264 * 512 * 2);
    _Float16* BF1  = (_Float16*)carve((size_t)528 * 512 * 2);
    _Float16* XB0  = (_Float16*)carve((size_t)N * 32 * 2);
    _Float16* X1B  = (_Float16*)carve((size_t)N * 64 * 2);
    float*    AGG0 = (float*)carve((size_t)N * 64 * 4);
    float*    AGG1 = (float*)carve((size_t)N * 64 * 4);

    int tbf = (264 + 528) * 512;
    prep_bf_both<<<(tbf + 255) / 256, 256, 0, stream>>>(w2_0, b2_0, BF0, w2_1, b2_1, BF1);
    node_root_cvt<<<(N * 64 + 255) / 256, 256, 0, stream>>>(x, root_0, bias_0, AGG0, XB0, N);

    int gblocks = (E + 63) / 64;
    edge_gemm<32><<<gblocks, 256, 0, stream>>>(ea, w1_0, b1_0, XB0, BF0, srcI, dstI, AGG0, E);

    mid_kernel<<<(N * 64 + 255) / 256, 256, 0, stream>>>(AGG0, root_1, bias_1, X1B, AGG1, N);

    edge_gemm<64><<<gblocks, 256, 0, stream>>>(ea, w1_1, b1_1, X1B, BF1, srcI, dstI, AGG1, E);

    final_relu<<<(N * 64 + 255) / 256, 256, 0, stream>>>(AGG1, out, N * 64);
}

// Round 6
// 187.891 us; speedup vs baseline: 3.4110x; 1.0583x over previous
//
#include <hip/hip_runtime.h>

typedef _Float16 v8h __attribute__((ext_vector_type(8)));
typedef float v16f __attribute__((ext_vector_type(16)));

// ---------------------------------------------------------------------------
// BF: B in MFMA-fragment order, padded to 66 ko (pad rows = 0).
// Fragment f = kk16*2 + nf holds at [lane*8 + j]:
//   B[k = kk16*16 + (lane>>5)*8 + j][o = nf*32 + (lane&31)]
// where B[k][o] = (ko<64) ? w2[ko, i*64+o] : (ko==64 ? b2[i*64+o] : 0),
// ko = k/IN, i = k%IN. kk16 = ko*PH + p.
// ---------------------------------------------------------------------------
__global__ void prep_bf_both(const float* __restrict__ w2_0, const float* __restrict__ b2_0,
                             _Float16* __restrict__ BF0,
                             const float* __restrict__ w2_1, const float* __restrict__ b2_1,
                             _Float16* __restrict__ BF1) {
    int idx = blockIdx.x * 256 + threadIdx.x;
    const int n0 = 264 * 512;   // layer0: 66 ko * 2 kk16/ko * 2 nf
    const int n1 = 528 * 512;   // layer1: 66 ko * 4 kk16/ko * 2 nf
    const float* w2; const float* b2; _Float16* BF; int IN, rel;
    if (idx < n0)           { w2 = w2_0; b2 = b2_0; BF = BF0; IN = 32; rel = idx; }
    else if (idx < n0 + n1) { w2 = w2_1; b2 = b2_1; BF = BF1; IN = 64; rel = idx - n0; }
    else return;
    int j = rel & 7, lane = (rel >> 3) & 63, f = rel >> 9;
    int nf = f & 1, kk16 = f >> 1;
    int ln = lane & 31, g2 = lane >> 5;
    int k = kk16 * 16 + g2 * 8 + j;
    int ko = k / IN, i = k - ko * IN;
    int o = nf * 32 + ln;
    float v = (ko < 64) ? w2[ko * (IN * 64) + i * 64 + o]
            : (ko == 64 ? b2[i * 64 + o] : 0.f);
    BF[rel] = (_Float16)v;
}

// agg0[n,o] = bias0[o] + sum_i x[n,i]*root0[i,o]; also emits x in f16
__global__ void node_root_cvt(const float* __restrict__ x, const float* __restrict__ root,
                              const float* __restrict__ bias, float* __restrict__ agg,
                              _Float16* __restrict__ xb, int N) {
    int idx = blockIdx.x * 256 + threadIdx.x;
    if (idx >= N * 64) return;
    int n = idx >> 6, o = idx & 63;
    float s = bias[o];
    const float* xr = x + (size_t)n * 32;
    #pragma unroll 8
    for (int i = 0; i < 32; ++i) s += xr[i] * root[i * 64 + o];
    agg[idx] = s;
    if (o < 32) xb[n * 32 + o] = (_Float16)xr[o];
}

// x1b = f16(relu(agg0)); agg1[n,o] = bias1[o] + sum_i relu(agg0[n,i])*root1[i,o]
__global__ void mid_kernel(const float* __restrict__ agg0, const float* __restrict__ root1,
                           const float* __restrict__ bias1, _Float16* __restrict__ x1b,
                           float* __restrict__ agg1, int N) {
    int idx = blockIdx.x * 256 + threadIdx.x;
    if (idx >= N * 64) return;
    int n = idx >> 6, o = idx & 63;
    const float* ar = agg0 + (size_t)n * 64;
    float s = bias1[o];
    #pragma unroll 8
    for (int i = 0; i < 64; ++i) s += fmaxf(ar[i], 0.f) * root1[i * 64 + o];
    agg1[idx] = s;
    x1b[idx] = (_Float16)fmaxf(agg0[idx], 0.f);
}

__global__ void final_relu(const float* __restrict__ agg1, float* __restrict__ out, int n) {
    int idx = blockIdx.x * 256 + threadIdx.x;
    if (idx < n) out[idx] = fmaxf(agg1[idx], 0.f);
}

// ---------------------------------------------------------------------------
// Edge GEMM v6: 64-edge tile, 4 waves. Wave w owns nf = w&1, K-half = w>>1,
// BOTH mf (2 accumulators) — each B fragment is read by exactly ONE wave, so
// there is NO barrier and NO LDS staging in the K-loop. B streams global→reg
// with a double-buffered (b/bn), fully-unrolled, constant-indexed pipeline.
// K-halves are combined via one LDS buffer + one barrier; one global atomic
// per output element.
// ---------------------------------------------------------------------------
template<int IN_C>
__global__ __launch_bounds__(256, 3)
void edge_gemm(const float* __restrict__ ea,
               const float* __restrict__ w1, const float* __restrict__ b1,
               const _Float16* __restrict__ xb, const _Float16* __restrict__ BF,
               const int* __restrict__ srcI, const int* __restrict__ dstI,
               float* __restrict__ agg, int E) {
    constexpr int PH  = IN_C / 16;        // fragments per ko per nf
    constexpr int CPR = IN_C / 8;         // 16B chunks per x row

    __shared__ __align__(16) _Float16 sh_x[64][IN_C];
    __shared__ _Float16 sh_r1[64][66];
    __shared__ float buf[64][65];
    __shared__ int sh_dst[64];

    int tid = threadIdx.x;
    int ebase = blockIdx.x * 64;
    int valid = E - ebase; if (valid > 64) valid = 64;

    if (tid < 64) {
        sh_dst[tid] = (tid < valid) ? dstI[ebase + tid] : 0;
        sh_r1[tid][64] = (_Float16)1.f;
        sh_r1[tid][65] = (_Float16)0.f;
    }
    // r1 tile computed in-kernel: relu(ea @ w1 + b1)
    for (int i = tid; i < 64 * 64; i += 256) {
        int e = i >> 6, j = i & 63;
        int ge = (e < valid) ? (ebase + e) : ebase;
        float a0 = ea[ge * 2], a1 = ea[ge * 2 + 1];
        sh_r1[e][j] = (_Float16)fmaxf(a0 * w1[j] + a1 * w1[64 + j] + b1[j], 0.f);
    }
    // gathered x tile
    for (int i = tid; i < 64 * CPR; i += 256) {
        int r = i / CPR, c = i - r * CPR;
        int sidx = (r < valid) ? srcI[ebase + r] : 0;
        *(uint4*)&sh_x[r][c * 8] = *(const uint4*)(xb + (size_t)sidx * IN_C + (size_t)c * 8);
    }
    __syncthreads();

    int wv = tid >> 6, lane = tid & 63, ln = lane & 31, g2 = lane >> 5;
    int nf = wv & 1, kh = wv >> 1;

    // x slices for both m-halves
    v8h xs0[PH], xs1[PH];
    #pragma unroll
    for (int p = 0; p < PH; ++p) {
        xs0[p] = *(const v8h*)&sh_x[ln][p * 16 + g2 * 8];
        xs1[p] = *(const v8h*)&sh_x[ln + 32][p * 16 + g2 * 8];
    }

    v16f acc0 = {0,0,0,0,0,0,0,0,0,0,0,0,0,0,0,0};
    v16f acc1 = acc0;

    // wave's fragment stream: frag(ko,p) at uint4 index (ko*PH+p)*128 + nf*64 + lane
    const uint4* bp = (const uint4*)BF + (size_t)nf * 64 + lane;
    int kb = kh * 33;                     // 33 ko per K-half (66 total incl pad)

    uint4 b[PH], bn[PH];
    auto LD = [&](uint4 (&d)[PH], int ko) {
        #pragma unroll
        for (int p = 0; p < PH; ++p) d[p] = bp[(size_t)(ko * PH + p) * 128];
    };
    auto FM = [&](uint4 (&d)[PH], int ko) {
        _Float16 sv0 = sh_r1[ln][ko];
        _Float16 sv1 = sh_r1[ln + 32][ko];
        #pragma unroll
        for (int p = 0; p < PH; ++p) {
            v8h bb; __builtin_memcpy(&bb, &d[p], 16);
            v8h a0 = xs0[p] * sv0;
            v8h a1 = xs1[p] * sv1;
            acc0 = __builtin_amdgcn_mfma_f32_32x32x16_f16(a0, bb, acc0, 0, 0, 0);
            acc1 = __builtin_amdgcn_mfma_f32_32x32x16_f16(a1, bb, acc1, 0, 0, 0);
        }
    };

    LD(b, kb);
    #pragma unroll 1
    for (int t = 0; t < 16; ++t) {        // ko pairs; b/bn double buffer
        LD(bn, kb + 2 * t + 1);
        FM(b,  kb + 2 * t);
        LD(b,  kb + 2 * t + 2);
        FM(bn, kb + 2 * t + 1);
    }
    FM(b, kb + 32);                       // 33rd ko

    // combine K-halves: kh=1 stores to LDS, kh=0 adds and does ONE global atomic
    int colb = nf * 32 + ln;
    if (kh == 1) {
        #pragma unroll
        for (int r = 0; r < 16; ++r) {
            int row = 4 * g2 + (r & 3) + 8 * (r >> 2);
            buf[row][colb]      = acc0[r];
            buf[row + 32][colb] = acc1[r];
        }
    }
    __syncthreads();
    if (kh == 0) {
        #pragma unroll
        for (int r = 0; r < 16; ++r) {
            int row = 4 * g2 + (r & 3) + 8 * (r >> 2);
            if (row < valid)
                atomicAdd(&agg[(size_t)sh_dst[row] * 64 + colb], acc0[r] + buf[row][colb]);
            int row1 = row + 32;
            if (row1 < valid)
                atomicAdd(&agg[(size_t)sh_dst[row1] * 64 + colb], acc1[r] + buf[row1][colb]);
        }
    }
}

// ---------------------------------------------------------------------------
extern "C" void kernel_launch(void* const* d_in, const int* in_sizes, int n_in,
                              void* d_out, int out_size, void* d_ws, size_t ws_size,
                              hipStream_t stream) {
    const float* x      = (const float*)d_in[0];
    const int*   ei     = (const int*)d_in[1];
    const float* ea     = (const float*)d_in[2];
    const float* w1_0   = (const float*)d_in[3];
    const float* b1_0   = (const float*)d_in[4];
    const float* w2_0   = (const float*)d_in[5];
    const float* b2_0   = (const float*)d_in[6];
    const float* root_0 = (const float*)d_in[7];
    const float* bias_0 = (const float*)d_in[8];
    const float* w1_1   = (const float*)d_in[9];
    const float* b1_1   = (const float*)d_in[10];
    const float* w2_1   = (const float*)d_in[11];
    const float* b2_1   = (const float*)d_in[12];
    const float* root_1 = (const float*)d_in[13];
    const float* bias_1 = (const float*)d_in[14];
    float* out = (float*)d_out;

    int N = in_sizes[0] / 32;
    int E = in_sizes[1] / 2;
    const int* srcI = ei;
    const int* dstI = ei + E;

    char* ws = (char*)d_ws;
    size_t off = 0;
    auto carve = [&](size_t bytes) {
        void* p = ws + off;
        off += (bytes + 255) & ~(size_t)255;
        return p;
    };
    _Float16* BF0  = (_Float16*)carve((size_t)264 * 512 * 2);
    _Float16* BF1  = (_Float16*)carve((size_t)528 * 512 * 2);
    _Float16* XB0  = (_Float16*)carve((size_t)N * 32 * 2);
    _Float16* X1B  = (_Float16*)carve((size_t)N * 64 * 2);
    float*    AGG0 = (float*)carve((size_t)N * 64 * 4);
    float*    AGG1 = (float*)carve((size_t)N * 64 * 4);

    int tbf = (264 + 528) * 512;
    prep_bf_both<<<(tbf + 255) / 256, 256, 0, stream>>>(w2_0, b2_0, BF0, w2_1, b2_1, BF1);
    node_root_cvt<<<(N * 64 + 255) / 256, 256, 0, stream>>>(x, root_0, bias_0, AGG0, XB0, N);

    int gblocks = (E + 63) / 64;
    edge_gemm<32><<<gblocks, 256, 0, stream>>>(ea, w1_0, b1_0, XB0, BF0, srcI, dstI, AGG0, E);

    mid_kernel<<<(N * 64 + 255) / 256, 256, 0, stream>>>(AGG0, root_1, bias_1, X1B, AGG1, N);

    edge_gemm<64><<<gblocks, 256, 0, stream>>>(ea, w1_1, b1_1, X1B, BF1, srcI, dstI, AGG1, E);

    final_relu<<<(N * 64 + 255) / 256, 256, 0, stream>>>(AGG1, out, N * 64);
}